// Round 1
// 212.128 us; speedup vs baseline: 1.0629x; 1.0629x over previous
//
#include <hip/hip_runtime.h>
#include <stdint.h>

// PerfeCT membership test — out[i] = +5 if query triple i's wrapped-int32 KEY
// matches any data triple's wrapped-int32 KEY, else -5.
//
// NUMERICS (R1-R5 prev session): JAX x64 disabled -> buffers are INT32; the
// reference computes _triple_key in int32, which WRAPS. Membership = equality
// of wrapped 32-bit keys (verified: absmax 0).
//
// PERF (this round): scan_data was latency-chain bound (77us, VALUBusy 17%,
// HBM 13%): wave-divergent probe loops ran for ~every wave (P(any of 64 lanes
// passes 10% bloom) ~ 99.9%), each a dependent 8B-load walk, 4x serial per
// group, on a table thrashed out of L2 by the streaming data. Fixes:
//   1) bucketized table: bucket-aligned inserts + 16B (2-entry) bucket loads
//      -> half the dependent trips per probe.
//   2) batched probes: the 4 candidates' bucket loads issue together, then
//      evaluate -> 1 memory stall per round instead of up to 16 per group.
//   3) non-temporal data-stream loads (nt) -> 120MB once-read stream stops
//      evicting the reused 2MB table / 64KB bloom from L2.
//   4) __launch_bounds__(1024,8) pins VGPR<=64 to keep 2 blocks/CU.

#define EMPTY64     0xFFFFFFFFFFFFFFFFULL
#define BLOOM_WORDS 16384u                 // 64 KB, power of two
#define BLOOM_MASK  (BLOOM_WORDS - 1u)

typedef unsigned int       v4u   __attribute__((ext_vector_type(4)));
typedef unsigned long long v2u64 __attribute__((ext_vector_type(2)));

__device__ __forceinline__ uint32_t key32(uint32_t h, uint32_t r, uint32_t t) {
    return (h * 15000u + r) * 15000u + t;  // int32 wrap semantics via uint32
}

__device__ __forceinline__ uint64_t mix64(uint64_t x) {
    x ^= x >> 30; x *= 0xbf58476d1ce4e5b9ULL;
    x ^= x >> 27; x *= 0x94d049bb133111ebULL;
    x ^= x >> 31;
    return x;
}

// Clear table (to EMPTY) and bloom (to 0) with 16B stores.
__global__ void clear_ws(uint4* __restrict__ table4, unsigned n_table4,
                         uint4* __restrict__ bloom4, unsigned n_bloom4) {
    unsigned i = blockIdx.x * blockDim.x + threadIdx.x;
    if (i < n_table4) table4[i] = make_uint4(~0u, ~0u, ~0u, ~0u);
    if (i < n_bloom4) bloom4[i] = make_uint4(0u, 0u, 0u, 0u);
}

__global__ void insert_queries(const int* __restrict__ heads,
                               const int* __restrict__ rels,
                               const int* __restrict__ tails,
                               unsigned long long* __restrict__ table,
                               unsigned tmask,
                               uint32_t* __restrict__ g_bloom,
                               float* __restrict__ out,
                               int Q) {
    int i = blockIdx.x * blockDim.x + threadIdx.x;
    if (i >= Q) return;
    out[i] = -5.0f;  // default: not a member
    uint32_t key = key32((uint32_t)heads[i], (uint32_t)rels[i], (uint32_t)tails[i]);
    uint64_t mix = mix64(key);
    // blocked bloom: one word, two bits
    uint32_t bm = (1u << ((mix >> 46) & 31u)) | (1u << ((mix >> 51) & 31u));
    atomicOr(&g_bloom[(mix >> 32) & BLOOM_MASK], bm);
    // open-addressing insert, BUCKET-ALIGNED start (even slot) so the scan
    // can walk aligned 16B pairs. Slots only go EMPTY->occupied, so every
    // entry's linear probe path stays occupied -> pair-walk termination at
    // the first EMPTY reaches all duplicates first.
    uint64_t entry = (uint64_t)key | ((uint64_t)(unsigned)i << 32);
    unsigned slot = ((unsigned)mix & (tmask >> 1)) << 1;     // even
    for (unsigned step = 0; step <= tmask; ++step) {         // bounded
        if (atomicCAS(&table[slot], EMPTY64, (unsigned long long)entry) == EMPTY64) break;
        slot = (slot + 1u) & tmask;
    }
}

// Walk aligned 2-entry buckets from bucket b until an EMPTY slot; write +5
// for every matching entry (duplicate query keys each have an entry).
__device__ __forceinline__ void probe_pairs(uint32_t key, unsigned b,
                                            const v2u64* __restrict__ tb,
                                            unsigned bmask,
                                            float* __restrict__ out) {
    for (unsigned step = 0; step <= bmask; ++step) {         // bounded
        v2u64 e = tb[b];
        bool le = (e.x == EMPTY64), he = (e.y == EMPTY64);
        if (!le && (uint32_t)e.x == key) out[e.x >> 32] = 5.0f;
        if (!he && (uint32_t)e.y == key) out[e.y >> 32] = 5.0f;
        if (le || he) return;
        b = (b + 1u) & bmask;
    }
}

__global__ __launch_bounds__(1024, 8)
void scan_data(const int* __restrict__ data, int N,
               const unsigned long long* __restrict__ table,
               unsigned tmask,
               const uint32_t* __restrict__ g_bloom,
               float* __restrict__ out) {
    __shared__ uint32_t bloom[BLOOM_WORDS];     // 64 KB -> 2 blocks/CU
    {   // stage bloom into LDS (16B vector copies)
        const uint4* src = (const uint4*)g_bloom;
        uint4* dst = (uint4*)bloom;
        for (unsigned w = threadIdx.x; w < BLOOM_WORDS / 4; w += blockDim.x)
            dst[w] = src[w];
    }
    __syncthreads();

    const unsigned tid    = blockIdx.x * blockDim.x + threadIdx.x;
    const unsigned stride = gridDim.x * blockDim.x;
    const unsigned bmask  = tmask >> 1;                      // bucket-index mask
    const v2u64* tb = (const v2u64*)table;

    if ((N & 3) == 0) {
        const int nq = N >> 2;
        const v4u* h4 = (const v4u*)data;
        const v4u* r4 = (const v4u*)(data + (size_t)N);
        const v4u* t4 = (const v4u*)(data + 2 * (size_t)N);
        for (unsigned q = tid; q < (unsigned)nq; q += stride) {
            // non-temporal: once-read stream, keep it out of L2
            v4u h = __builtin_nontemporal_load(&h4[q]);
            v4u r = __builtin_nontemporal_load(&r4[q]);
            v4u t = __builtin_nontemporal_load(&t4[q]);

            uint32_t k0 = key32(h.x, r.x, t.x);
            uint32_t k1 = key32(h.y, r.y, t.y);
            uint32_t k2 = key32(h.z, r.z, t.z);
            uint32_t k3 = key32(h.w, r.w, t.w);
            uint64_t m0 = mix64(k0), m1 = mix64(k1), m2 = mix64(k2), m3 = mix64(k3);

            // bloom tests (independent LDS reads, overlapped)
            uint32_t w0 = bloom[(uint32_t)(m0 >> 32) & BLOOM_MASK];
            uint32_t w1 = bloom[(uint32_t)(m1 >> 32) & BLOOM_MASK];
            uint32_t w2 = bloom[(uint32_t)(m2 >> 32) & BLOOM_MASK];
            uint32_t w3 = bloom[(uint32_t)(m3 >> 32) & BLOOM_MASK];
            uint32_t bm0 = (1u << ((m0 >> 46) & 31u)) | (1u << ((m0 >> 51) & 31u));
            uint32_t bm1 = (1u << ((m1 >> 46) & 31u)) | (1u << ((m1 >> 51) & 31u));
            uint32_t bm2 = (1u << ((m2 >> 46) & 31u)) | (1u << ((m2 >> 51) & 31u));
            uint32_t bm3 = (1u << ((m3 >> 46) & 31u)) | (1u << ((m3 >> 51) & 31u));

            bool d0 = (w0 & bm0) != bm0;
            bool d1 = (w1 & bm1) != bm1;
            bool d2 = (w2 & bm2) != bm2;
            bool d3 = (w3 & bm3) != bm3;
            unsigned b0 = (unsigned)m0 & bmask;
            unsigned b1 = (unsigned)m1 & bmask;
            unsigned b2 = (unsigned)m2 & bmask;
            unsigned b3 = (unsigned)m3 & bmask;

            // batched bucket walk: all pending loads issue together, then
            // evaluate; one memory stall per round, not per candidate.
            for (unsigned g = 0; (g <= bmask) && !(d0 && d1 && d2 && d3); ++g) {
                v2u64 e0, e1, e2, e3;
                if (!d0) e0 = tb[b0];
                if (!d1) e1 = tb[b1];
                if (!d2) e2 = tb[b2];
                if (!d3) e3 = tb[b3];
#define EVAL_PAIR(e, k, b, d)                                              \
                if (!(d)) {                                                \
                    bool le = ((e).x == EMPTY64), he = ((e).y == EMPTY64); \
                    if (!le && (uint32_t)(e).x == (k)) out[(e).x >> 32] = 5.0f; \
                    if (!he && (uint32_t)(e).y == (k)) out[(e).y >> 32] = 5.0f; \
                    if (le || he) (d) = true;                              \
                    else (b) = ((b) + 1u) & bmask;                         \
                }
                EVAL_PAIR(e0, k0, b0, d0)
                EVAL_PAIR(e1, k1, b1, d1)
                EVAL_PAIR(e2, k2, b2, d2)
                EVAL_PAIR(e3, k3, b3, d3)
#undef EVAL_PAIR
            }
        }
    } else {
        for (unsigned i = tid; i < (unsigned)N; i += stride) {
            uint32_t key = key32((uint32_t)data[i],
                                 (uint32_t)data[(size_t)N + i],
                                 (uint32_t)data[2 * (size_t)N + i]);
            uint64_t mix = mix64(key);
            uint32_t w  = bloom[(uint32_t)(mix >> 32) & BLOOM_MASK];
            uint32_t bm = (1u << ((mix >> 46) & 31u)) | (1u << ((mix >> 51) & 31u));
            if ((w & bm) != bm) continue;
            probe_pairs(key, (unsigned)mix & bmask, tb, bmask, out);
        }
    }
}

extern "C" void kernel_launch(void* const* d_in, const int* in_sizes, int n_in,
                              void* d_out, int out_size, void* d_ws, size_t ws_size,
                              hipStream_t stream) {
    const int* heads = (const int*)d_in[0];
    const int* rels  = (const int*)d_in[1];
    const int* tails = (const int*)d_in[2];
    const int* data  = (const int*)d_in[3];   // [3, N] row-major int32
    float* out = (float*)d_out;

    const int Q = in_sizes[0];
    const int N = in_sizes[3] / 3;

    // ws layout: table (pow2 entries) then bloom (64 KB).
    size_t cap = 1ull << 18;                  // 2 MB, load factor ~0.38 @ Q=100K
    if (cap * 8 + BLOOM_WORDS * 4 > ws_size) cap = 1ull << 17;
    if (cap * 8 + BLOOM_WORDS * 4 > ws_size) return;  // can't run
    unsigned tmask = (unsigned)(cap - 1);
    unsigned long long* table = (unsigned long long*)d_ws;
    uint32_t* g_bloom = (uint32_t*)((char*)d_ws + cap * 8);

    {   // 1) clear table + bloom (capture-safe: kernel, no runtime APIs)
        unsigned n_table4 = (unsigned)(cap / 2);        // 2 u64 per uint4
        unsigned n_bloom4 = BLOOM_WORDS / 4;
        unsigned n = n_table4 > n_bloom4 ? n_table4 : n_bloom4;
        dim3 block(256), grid((n + 255) / 256);
        clear_ws<<<grid, block, 0, stream>>>((uint4*)table, n_table4,
                                             (uint4*)g_bloom, n_bloom4);
    }
    {   // 2) insert queries: bloom bits + table entries + out := -5
        dim3 block(256), grid((Q + 255) / 256);
        insert_queries<<<grid, block, 0, stream>>>(heads, rels, tails, table, tmask,
                                                   g_bloom, out, Q);
    }
    {   // 3) scan data: LDS bloom prefilter, batched bucket probes
        dim3 block(1024), grid(512);          // 2 blocks/CU
        scan_data<<<grid, block, 0, stream>>>(data, N, table, tmask, g_bloom, out);
    }
}